// Round 1
// baseline (289.860 us; speedup 1.0000x reference)
//
#include <hip/hip_runtime.h>
#include <hip/hip_bf16.h>

#define BATCH 16
#define SEQ   2048
#define DK    128

typedef __attribute__((ext_vector_type(8))) short short8v;   // 8 bf16 in 4 VGPRs
typedef __attribute__((ext_vector_type(4))) float float4v;   // MFMA 16x16 C/D

__device__ inline short f2bf(float f) {
    __hip_bfloat16 h = __float2bfloat16(f);
    unsigned short u;
    __builtin_memcpy(&u, &h, sizeof(u));
    return (short)u;
}

// Flash attention fwd. One wave = 16 q rows. KV tiles of 16.
// S^T tile via mfma(K, Q): lane holds S^T[kv=4*grp+r][q=lane&15] in s[r]
// (verified C/D layout: col=lane&15, row=(lane>>4)*4+reg).
// PV via zero-padded 16x16x32 mfma: A = {p0..p3,0,0,0,0}, B = V rows duplicated.
__global__ __launch_bounds__(256)
void attn_fwd_kernel(const float* __restrict__ q,
                     const float* __restrict__ k,
                     const float* __restrict__ v,
                     float* __restrict__ out)
{
    const int lane = threadIdx.x & 63;
    const int wave = threadIdx.x >> 6;           // 0..3
    const int b    = blockIdx.y;
    const int q0   = blockIdx.x * 64 + wave * 16; // q base within batch

    const int row = lane & 15;   // A-frag row / C-frag col
    const int grp = lane >> 4;   // 0..3

    const float* qb = q + ((size_t)b * SEQ + q0) * DK;
    const float* kb = k + (size_t)b * SEQ * DK;
    const float* vb = v + (size_t)b * SEQ * DK;

    // Q fragments: lane holds Q[q0+row][c*32 + grp*8 + 0..7], c=0..3
    short8v qf[4];
#pragma unroll
    for (int c = 0; c < 4; ++c) {
        const float* p = qb + row * DK + c * 32 + grp * 8;
        float4 x = *reinterpret_cast<const float4*>(p);
        float4 y = *reinterpret_cast<const float4*>(p + 4);
        short8v t;
        t[0] = f2bf(x.x); t[1] = f2bf(x.y); t[2] = f2bf(x.z); t[3] = f2bf(x.w);
        t[4] = f2bf(y.x); t[5] = f2bf(y.y); t[6] = f2bf(y.z); t[7] = f2bf(y.w);
        qf[c] = t;
    }

    float m_run = -1e30f;
    float l_run = 0.0f;
    float4v o[8];
#pragma unroll
    for (int i = 0; i < 8; ++i) { o[i][0] = 0.f; o[i][1] = 0.f; o[i][2] = 0.f; o[i][3] = 0.f; }

    const float scale = 0.08838834764831845f;  // 1/sqrt(128)

    for (int kv0 = 0; kv0 < SEQ; kv0 += 16) {
        // K fragments (same lane pattern as Q)
        short8v kf[4];
        const float* kp0 = kb + (size_t)(kv0 + row) * DK + grp * 8;
#pragma unroll
        for (int c = 0; c < 4; ++c) {
            const float* p = kp0 + c * 32;
            float4 x = *reinterpret_cast<const float4*>(p);
            float4 y = *reinterpret_cast<const float4*>(p + 4);
            short8v t;
            t[0] = f2bf(x.x); t[1] = f2bf(x.y); t[2] = f2bf(x.z); t[3] = f2bf(x.w);
            t[4] = f2bf(y.x); t[5] = f2bf(y.y); t[6] = f2bf(y.z); t[7] = f2bf(y.w);
            kf[c] = t;
        }
        // V fragments: vf[dblk][j] = V[kv0 + 4*grp + (j&3)][dblk*16 + row] (j>=4 dup; A side is 0 there)
        short8v vf[8];
#pragma unroll
        for (int dblk = 0; dblk < 8; ++dblk) {
            const float* p = vb + (size_t)(kv0 + 4 * grp) * DK + dblk * 16 + row;
            short b0 = f2bf(p[0]);
            short b1 = f2bf(p[DK]);
            short b2 = f2bf(p[2 * DK]);
            short b3 = f2bf(p[3 * DK]);
            short8v t;
            t[0] = b0; t[1] = b1; t[2] = b2; t[3] = b3;
            t[4] = b0; t[5] = b1; t[6] = b2; t[7] = b3;
            vf[dblk] = t;
        }

        // S^T tile: D = K_tile(16x128) . Q^T(128x16), accumulated over 4 d-chunks
        float4v s; s[0] = 0.f; s[1] = 0.f; s[2] = 0.f; s[3] = 0.f;
#pragma unroll
        for (int c = 0; c < 4; ++c)
            s = __builtin_amdgcn_mfma_f32_16x16x32_bf16(kf[c], qf[c], s, 0, 0, 0);

        // online softmax for q = row; this lane holds kv = 4*grp + r
        float sv[4];
        float tmax = -1e30f;
#pragma unroll
        for (int r = 0; r < 4; ++r) { sv[r] = s[r] * scale; tmax = fmaxf(tmax, sv[r]); }
        tmax = fmaxf(tmax, __shfl_xor(tmax, 16));
        tmax = fmaxf(tmax, __shfl_xor(tmax, 32));
        const float mnew = fmaxf(m_run, tmax);

        float pr[4];
        float tsum = 0.f;
#pragma unroll
        for (int r = 0; r < 4; ++r) { pr[r] = __expf(sv[r] - mnew); tsum += pr[r]; }
        tsum += __shfl_xor(tsum, 16);
        tsum += __shfl_xor(tsum, 32);

        const float alpha = __expf(m_run - mnew);
        l_run = l_run * alpha + tsum;
        m_run = mnew;

        // rescale O: O rows are q' = grp*4 + r; alpha lives at lane q' (lanes 0..15)
        float aq[4];
#pragma unroll
        for (int r = 0; r < 4; ++r) aq[r] = __shfl(alpha, grp * 4 + r);
#pragma unroll
        for (int dblk = 0; dblk < 8; ++dblk)
#pragma unroll
            for (int r = 0; r < 4; ++r) o[dblk][r] *= aq[r];

        // P fragment: A rows q=lane&15, k-slots 8*grp+j -> kv=4*grp+j for j<4, zero for j>=4
        short8v pf;
        pf[0] = f2bf(pr[0]); pf[1] = f2bf(pr[1]); pf[2] = f2bf(pr[2]); pf[3] = f2bf(pr[3]);
        pf[4] = 0; pf[5] = 0; pf[6] = 0; pf[7] = 0;

#pragma unroll
        for (int dblk = 0; dblk < 8; ++dblk)
            o[dblk] = __builtin_amdgcn_mfma_f32_16x16x32_bf16(pf, vf[dblk], o[dblk], 0, 0, 0);
    }

    // epilogue: divide by l (per O-row q' = grp*4 + r), write fp32
    const float linv = 1.0f / l_run;   // valid for q = row; redistribute to O rows
    float li[4];
#pragma unroll
    for (int r = 0; r < 4; ++r) li[r] = __shfl(linv, grp * 4 + r);

    float* ob = out + ((size_t)b * SEQ + q0) * DK;
#pragma unroll
    for (int dblk = 0; dblk < 8; ++dblk)
#pragma unroll
        for (int r = 0; r < 4; ++r)
            ob[(size_t)(grp * 4 + r) * DK + dblk * 16 + row] = o[dblk][r] * li[r];
}

extern "C" void kernel_launch(void* const* d_in, const int* in_sizes, int n_in,
                              void* d_out, int out_size, void* d_ws, size_t ws_size,
                              hipStream_t stream) {
    const float* q = (const float*)d_in[0];
    const float* k = (const float*)d_in[1];
    const float* v = (const float*)d_in[2];
    float* out = (float*)d_out;
    dim3 grid(SEQ / 64, BATCH);
    dim3 block(256);
    hipLaunchKernelGGL(attn_fwd_kernel, grid, block, 0, stream, q, k, v, out);
}